// Round 1
// baseline (428.367 us; speedup 1.0000x reference)
//
#include <hip/hip_runtime.h>

// InverseHaar: in (B=16, C=256, H=128, W=128) fp32 -> out (B=16, G=64, 2H=256, 2W=256) fp32
// c = quad*G + g ; a=quad0, h=quad1, v=quad2, d=quad3
// out[b,g,2y,2x]=tl  out[b,g,2y,2x+1]=tr  out[b,g,2y+1,2x]=bl  out[b,g,2y+1,2x+1]=br

constexpr int B = 16, C = 256, H = 128, W = 128;
constexpr int G = C / 4;     // 64
constexpr int W4 = W / 4;    // 32 float4-chunks per row
constexpr int PLANE = G * H * W;   // 1,048,576 elements between quads

__global__ __launch_bounds__(256) void inv_haar_kernel(const float* __restrict__ in,
                                                       float* __restrict__ out) {
    int tid = blockIdx.x * blockDim.x + threadIdx.x;
    // decompose tid -> (b, g, y, x4); all power-of-2 extents
    int x4 = tid & (W4 - 1);
    int t  = tid >> 5;          // / 32
    int y  = t & (H - 1);
    t >>= 7;                    // / 128
    int g  = t & (G - 1);
    int b  = t >> 6;            // / 64

    int a_off = (((b * C + g) * H) + y) * W + (x4 << 2);
    const float4 av = *(const float4*)(in + a_off);
    const float4 hv = *(const float4*)(in + a_off + PLANE);
    const float4 vv = *(const float4*)(in + a_off + 2 * PLANE);
    const float4 dv = *(const float4*)(in + a_off + 3 * PLANE);

    float4 top0, top1, bot0, bot1;

    #define HAAR(A, Hh, V, D, TL, TR, BL, BR)      \
        {                                          \
            float s0 = (A) + (Hh), s1 = (V) + (D); \
            float d0 = (A) - (Hh), d1 = (V) - (D); \
            TL = (s0 + s1) * 0.25f;                \
            TR = (d0 + d1) * 0.25f;                \
            BL = (s0 - s1) * 0.25f;                \
            BR = (d0 - d1) * 0.25f;                \
        }

    HAAR(av.x, hv.x, vv.x, dv.x, top0.x, top0.y, bot0.x, bot0.y);
    HAAR(av.y, hv.y, vv.y, dv.y, top0.z, top0.w, bot0.z, bot0.w);
    HAAR(av.z, hv.z, vv.z, dv.z, top1.x, top1.y, bot1.x, bot1.y);
    HAAR(av.w, hv.w, vv.w, dv.w, top1.z, top1.w, bot1.z, bot1.w);
    #undef HAAR

    int o_top = (((b * G + g) * (2 * H)) + 2 * y) * (2 * W) + (x4 << 3);
    int o_bot = o_top + 2 * W;

    *(float4*)(out + o_top)     = top0;
    *(float4*)(out + o_top + 4) = top1;
    *(float4*)(out + o_bot)     = bot0;
    *(float4*)(out + o_bot + 4) = bot1;
}

extern "C" void kernel_launch(void* const* d_in, const int* in_sizes, int n_in,
                              void* d_out, int out_size, void* d_ws, size_t ws_size,
                              hipStream_t stream) {
    const float* in = (const float*)d_in[0];
    float* out = (float*)d_out;
    const int total_threads = B * G * H * W4;   // 4,194,304
    const int block = 256;
    const int grid = total_threads / block;     // 16,384
    inv_haar_kernel<<<grid, block, 0, stream>>>(in, out);
}